// Round 6
// baseline (461.159 us; speedup 1.0000x reference)
//
#include <hip/hip_runtime.h>
#include <hip/hip_bf16.h>
#include <cstdint>
#include <cstddef>

// Problem constants: B=4,S=2048,D=1024,E=32,H=128,K=2
#define NTOK 8192
#define DIM  1024
#define NEXP 32
#define NH   128
#define TT   32               // tokens per FFN tile
#define SLOTS 8               // tile slots per (expert,choice); grid-stride
#define LCAP2 512             // per-(expert,choice) capacity (mean 256, 16 sigma)
#define RT   32               // tokens per router block

typedef __attribute__((ext_vector_type(8))) short short8;
typedef __attribute__((ext_vector_type(4))) short short4_;
typedef __attribute__((ext_vector_type(4))) float float4_;

static __device__ __forceinline__ unsigned short f2bf(float f) {
  unsigned u = __float_as_uint(f);
  return (unsigned short)((u + 0x7fffu + ((u >> 16) & 1u)) >> 16);
}
static __device__ __forceinline__ float bf2f(unsigned short h) {
  return __uint_as_float(((unsigned)h) << 16);
}
// 8 consecutive fp32 -> short8 of bf16 via packed cvt (RNE)
static __device__ __forceinline__ short8 ld_cvt8(const float* p) {
  float4 f0 = *(const float4*)(p);
  float4 f1 = *(const float4*)(p + 4);
  union { short8 s; __hip_bfloat162 h[4]; } u;
  u.h[0] = __float22bfloat162_rn(float2{f0.x, f0.y});
  u.h[1] = __float22bfloat162_rn(float2{f0.z, f0.w});
  u.h[2] = __float22bfloat162_rn(float2{f1.x, f1.y});
  u.h[3] = __float22bfloat162_rn(float2{f1.z, f1.w});
  return u.s;
}

// ---------------- Prep: per-expert weight transpose + fp32->bf16 -----------
// grid (128, 32): bid.y = expert; bid.x<128 tiles.  wk [E][D][H]->[E][H][D],
// wv [E][H][D_cols]... handled by two launches worth folded in x: first 64
// tiles wk is wrong split -- keep R4's proven form: grid.x in [0,128) per
// matrix, launched as 2D grid (128, NEXP) twice via z? Simpler: 1D grid 8192.
__global__ __launch_bounds__(256) void transpose_cvt_kernel(
    const float* __restrict__ w_keys, const float* __restrict__ w_values,
    unsigned short* __restrict__ wk_t, unsigned short* __restrict__ wv_t)
{
  __shared__ float tile[32][33];
  const int bid = blockIdx.x;
  const int tid = threadIdx.x;
  const float* src; unsigned short* dst; int R, C, lb;
  if (bid < 4096) { src = w_keys;   dst = wk_t; R = DIM; C = NH;  lb = bid; }
  else            { src = w_values; dst = wv_t; R = NH;  C = DIM; lb = bid - 4096; }
  const int e   = lb >> 7;            // 128 tiles per expert
  const int t   = lb & 127;
  const int tpc = C >> 5;
  const int r0  = (t / tpc) * 32;
  const int c0  = (t % tpc) * 32;
  const float* s = src + (size_t)e * R * C;
  unsigned short* d = dst + (size_t)e * R * C;

  const int i = tid >> 3;             // 0..31
  const int j = (tid & 7) * 4;        // 0..28
  float4 v = *(const float4*)(s + (size_t)(r0 + i) * C + c0 + j);
  tile[i][j] = v.x; tile[i][j + 1] = v.y; tile[i][j + 2] = v.z; tile[i][j + 3] = v.w;
  __syncthreads();
  unsigned lo = (unsigned)f2bf(tile[j + 0][i]) | ((unsigned)f2bf(tile[j + 1][i]) << 16);
  unsigned hi = (unsigned)f2bf(tile[j + 2][i]) | ((unsigned)f2bf(tile[j + 3][i]) << 16);
  uint2 u; u.x = lo; u.y = hi;
  *(uint2*)(d + (size_t)(c0 + i) * R + r0 + j) = u;
}

// ---------------- Router: w_sel in VGPRs, 8 FMA per ds_read_b128 -----------
// 256 blocks x 128 threads, 32 tokens/block.
// thread: p = tid&15 -> experts {p, p+16}; tq = tid>>4 -> tokens tq*4..+3.
__global__ __launch_bounds__(128) void router_kernel(
    const float* __restrict__ x, const float* __restrict__ w_sel,
    int* __restrict__ counts, unsigned* __restrict__ list)
{
  __shared__ __align__(16) float xs_t[32][36];   // [d-in-chunk][token]
  __shared__ float sp[RT][33];                   // logits [token][expert]

  const int tid  = threadIdx.x;
  const int tok0 = blockIdx.x * RT;
  const int p    = tid & 15;
  const int tq   = tid >> 4;          // 0..7

  // staging map: token st = tid>>2 (0..31), d8 = (tid&3)*8
  const int st = tid >> 2;
  const int d8 = (tid & 3) * 8;

  float acc[2][4];
  #pragma unroll
  for (int h = 0; h < 2; ++h)
    #pragma unroll
    for (int k = 0; k < 4; ++k) acc[h][k] = 0.f;

  for (int dc = 0; dc < DIM; dc += 32) {
    // stage x chunk [32 tok][32 d] transposed
    const float* xp = x + (size_t)(tok0 + st) * DIM + dc + d8;
    float4 a0 = *(const float4*)(xp);
    float4 a1 = *(const float4*)(xp + 4);
    xs_t[d8 + 0][st] = a0.x; xs_t[d8 + 1][st] = a0.y;
    xs_t[d8 + 2][st] = a0.z; xs_t[d8 + 3][st] = a0.w;
    xs_t[d8 + 4][st] = a1.x; xs_t[d8 + 5][st] = a1.y;
    xs_t[d8 + 6][st] = a1.z; xs_t[d8 + 7][st] = a1.w;

    // w_sel chunk for this thread's 2 experts -> 64 VGPRs (global, L2-hot)
    float4 w0[8], w1[8];
    const float* wp0 = w_sel + (size_t)p * DIM + dc;
    const float* wp1 = w_sel + (size_t)(p + 16) * DIM + dc;
    #pragma unroll
    for (int q = 0; q < 8; ++q) { w0[q] = *(const float4*)(wp0 + q * 4);
                                  w1[q] = *(const float4*)(wp1 + q * 4); }
    __syncthreads();

    #pragma unroll 8
    for (int jj = 0; jj < 32; ++jj) {
      float4 xv = *(const float4*)&xs_t[jj][tq * 4];
      const float wa = ((const float*)w0)[jj];
      const float wb = ((const float*)w1)[jj];
      acc[0][0] += xv.x * wa; acc[0][1] += xv.y * wa;
      acc[0][2] += xv.z * wa; acc[0][3] += xv.w * wa;
      acc[1][0] += xv.x * wb; acc[1][1] += xv.y * wb;
      acc[1][2] += xv.z * wb; acc[1][3] += xv.w * wb;
    }
    __syncthreads();
  }

  #pragma unroll
  for (int h = 0; h < 2; ++h)
    #pragma unroll
    for (int k = 0; k < 4; ++k)
      sp[tq * 4 + k][p + 16 * h] = acc[h][k];
  __syncthreads();

  if (tid < RT) {
    const int t = tid;
    float m1 = -1e30f, m2 = -1e30f;
    int i1 = 0, i2 = 0;
    for (int ee = 0; ee < NEXP; ++ee) {
      float v = sp[t][ee];
      if (v > m1)      { m2 = m1; i2 = i1; m1 = v; i1 = ee; }
      else if (v > m2) { m2 = v; i2 = ee; }
    }
    const int token = tok0 + t;
    float g1 = 1.f / (1.f + __expf(-m1));
    float g2 = 1.f / (1.f + __expf(-m2));
    int p1 = atomicAdd(&counts[i1 * 2 + 0], 1);
    if (p1 < LCAP2) list[(i1 * 2 + 0) * LCAP2 + p1] = ((unsigned)f2bf(g1) << 16) | (unsigned)token;
    int p2 = atomicAdd(&counts[i2 * 2 + 1], 1);
    if (p2 < LCAP2) list[(i2 * 2 + 1) * LCAP2 + p2] = ((unsigned)f2bf(g2) << 16) | (unsigned)token;
  }
}

// ---------------- FFN: one launch, both choices, barrier-free K-loop -------
// grid 512: e = bid&31 (XCD-local weights), choice = (bid>>5)&1, slot = bid>>6.
// Phase A: S^T = relu(Wk @ X^T)*g -- A from wk_t (bf16), B gathered fp32 x
// with inline packed cvt. Phase B: out^T = Wv^T @ S, K=128 via LDS scores.
// choice 0 -> plain f32 stores to out (full coverage); choice 1 -> bf16 cont.
__global__ __launch_bounds__(256, 4) void ffn_kernel(
    const float* __restrict__ x,
    const unsigned short* __restrict__ wk_t,   // bf16 [E][H][D]
    const unsigned short* __restrict__ wv_t,   // bf16 [E][D][H]
    float* __restrict__ out,
    unsigned short* __restrict__ cont,         // bf16 [NTOK][DIM]
    const int* __restrict__ counts, const unsigned* __restrict__ list)
{
  const int bid    = blockIdx.x;
  const int e      = bid & 31;
  const int choice = (bid >> 5) & 1;
  const int slot   = bid >> 6;               // 0..7
  const int cnt    = min(counts[e * 2 + choice], LCAP2);

  __shared__ __align__(16) unsigned short ss2[16][TT][8];  // S [k>>3][t][k&7]
  __shared__ int   toks[TT];
  __shared__ float gates[TT];

  const int tid  = threadIdx.x;
  const int wave = tid >> 6;
  const int lane = tid & 63;
  const int quad = lane >> 4;
  const int l16  = lane & 15;

  const unsigned short* wkb = wk_t + (size_t)e * NH * DIM;
  const unsigned short* wvb = wv_t + (size_t)e * DIM * NH;
  const unsigned* lst = list + (size_t)(e * 2 + choice) * LCAP2;

  for (int t0 = slot * TT; t0 < cnt; t0 += SLOTS * TT) {
    const int n_tok = min(TT, cnt - t0);
    __syncthreads();                         // guard toks/ss2 reuse
    if (tid < TT) {
      int valid = tid < n_tok;
      unsigned en = valid ? lst[t0 + tid] : 0u;
      toks[tid]  = (int)(en & 0xffffu);
      gates[tid] = valid ? bf2f((unsigned short)(en >> 16)) : 0.f;
    }
    __syncthreads();

    // ---- Phase A: wave handles h-tiles {2w,2w+1} x token-tiles {0,1}
    const float* xg0 = x + (size_t)toks[l16]      * DIM + quad * 8;
    const float* xg1 = x + (size_t)toks[16 + l16] * DIM + quad * 8;
    const unsigned short* wg0 = wkb + (size_t)((wave * 2 + 0) * 16 + l16) * DIM + quad * 8;
    const unsigned short* wg1 = wkb + (size_t)((wave * 2 + 1) * 16 + l16) * DIM + quad * 8;

    float4_ accA[2][2];
    #pragma unroll
    for (int i = 0; i < 2; ++i)
      #pragma unroll
      for (int j = 0; j < 2; ++j) accA[i][j] = (float4_){0.f, 0.f, 0.f, 0.f};

    #pragma unroll 4
    for (int ks = 0; ks < 32; ++ks) {
      const int off = ks * 32;
      short8 a0 = *(const short8*)(wg0 + off);
      short8 a1 = *(const short8*)(wg1 + off);
      short8 b0 = ld_cvt8(xg0 + off);
      short8 b1 = ld_cvt8(xg1 + off);
      accA[0][0] = __builtin_amdgcn_mfma_f32_16x16x32_bf16(a0, b0, accA[0][0], 0, 0, 0);
      accA[0][1] = __builtin_amdgcn_mfma_f32_16x16x32_bf16(a0, b1, accA[0][1], 0, 0, 0);
      accA[1][0] = __builtin_amdgcn_mfma_f32_16x16x32_bf16(a1, b0, accA[1][0], 0, 0, 0);
      accA[1][1] = __builtin_amdgcn_mfma_f32_16x16x32_bf16(a1, b1, accA[1][1], 0, 0, 0);
    }

    // epilogue A: relu * gate -> bf16 scores, phase-B B-frag layout
    #pragma unroll
    for (int ht = 0; ht < 2; ++ht) {
      const int hb = (wave * 2 + ht) * 2 + (quad >> 1);
      #pragma unroll
      for (int tt = 0; tt < 2; ++tt) {
        const int t = tt * 16 + l16;
        const float g = gates[t];
        short4_ w;
        #pragma unroll
        for (int r = 0; r < 4; ++r)
          w[r] = (short)f2bf(fmaxf(accA[ht][tt][r], 0.f) * g);
        *(short4_*)&ss2[hb][t][(quad & 1) * 4] = w;
      }
    }
    __syncthreads();

    // ---- Phase B: out^T = Wv^T @ S, two d-halves sequentially
    #pragma unroll 1
    for (int dh = 0; dh < 2; ++dh) {
      float4_ accB[8][2];
      #pragma unroll
      for (int i = 0; i < 8; ++i)
        #pragma unroll
        for (int j = 0; j < 2; ++j) accB[i][j] = (float4_){0.f, 0.f, 0.f, 0.f};

      #pragma unroll
      for (int ks = 0; ks < 4; ++ks) {
        short8 b0 = *(const short8*)&ss2[ks * 4 + quad][l16][0];
        short8 b1 = *(const short8*)&ss2[ks * 4 + quad][16 + l16][0];
        #pragma unroll
        for (int i = 0; i < 8; ++i) {
          const int d = (dh * 32 + wave * 8 + i) * 16 + l16;
          short8 a = *(const short8*)(wvb + (size_t)d * NH + ks * 32 + quad * 8);
          accB[i][0] = __builtin_amdgcn_mfma_f32_16x16x32_bf16(a, b0, accB[i][0], 0, 0, 0);
          accB[i][1] = __builtin_amdgcn_mfma_f32_16x16x32_bf16(a, b1, accB[i][1], 0, 0, 0);
        }
      }

      #pragma unroll
      for (int tt = 0; tt < 2; ++tt) {
        const int t = tt * 16 + l16;
        if (t < n_tok) {
          const size_t rbase = (size_t)toks[t] * DIM +
                               (size_t)(dh * 32 + wave * 8) * 16 + quad * 4;
          if (choice == 0) {
            float* rowp = out + rbase;
            #pragma unroll
            for (int i = 0; i < 8; ++i) {
              float4 v;
              v.x = accB[i][tt][0]; v.y = accB[i][tt][1];
              v.z = accB[i][tt][2]; v.w = accB[i][tt][3];
              *(float4*)(rowp + i * 16) = v;
            }
          } else {
            unsigned short* rowp = cont + rbase;
            #pragma unroll
            for (int i = 0; i < 8; ++i) {
              union { uint2 u; __hip_bfloat162 h[2]; } pk;
              pk.h[0] = __float22bfloat162_rn(float2{accB[i][tt][0], accB[i][tt][1]});
              pk.h[1] = __float22bfloat162_rn(float2{accB[i][tt][2], accB[i][tt][3]});
              *(uint2*)(rowp + i * 16) = pk.u;
            }
          }
        }
      }
    }
  }
}

// ---------------- Combine: out += cont (bf16) ------------------------------
__global__ __launch_bounds__(256) void combine_kernel(
    const unsigned short* __restrict__ cont, float* __restrict__ out)
{
  size_t i = ((size_t)blockIdx.x * 256 + threadIdx.x) * 8;
  uint4 c = *(const uint4*)(cont + i);
  float4 o0 = *(const float4*)(out + i);
  float4 o1 = *(const float4*)(out + i + 4);
  o0.x += bf2f((unsigned short)(c.x & 0xffff));
  o0.y += bf2f((unsigned short)(c.x >> 16));
  o0.z += bf2f((unsigned short)(c.y & 0xffff));
  o0.w += bf2f((unsigned short)(c.y >> 16));
  o1.x += bf2f((unsigned short)(c.z & 0xffff));
  o1.y += bf2f((unsigned short)(c.z >> 16));
  o1.z += bf2f((unsigned short)(c.w & 0xffff));
  o1.w += bf2f((unsigned short)(c.w >> 16));
  *(float4*)(out + i)     = o0;
  *(float4*)(out + i + 4) = o1;
}

extern "C" void kernel_launch(void* const* d_in, const int* in_sizes, int n_in,
                              void* d_out, int out_size, void* d_ws, size_t ws_size,
                              hipStream_t stream) {
  (void)in_sizes; (void)n_in; (void)ws_size; (void)out_size;
  const float* x        = (const float*)d_in[0];
  const float* w_sel    = (const float*)d_in[1];
  const float* w_keys   = (const float*)d_in[2];
  const float* w_values = (const float*)d_in[3];
  float* out = (float*)d_out;

  // workspace (~33.0 MB; <= 33.1 MB proven available in R5)
  char* ws = (char*)d_ws;
  size_t off = 0;
  int*            counts = (int*)(ws + off);            off += 4096;
  unsigned*       list   = (unsigned*)(ws + off);       off += (size_t)NEXP * 2 * LCAP2 * 4; // 128 KB
  unsigned short* wk_t   = (unsigned short*)(ws + off); off += (size_t)NEXP * NH * DIM * 2;  // 8 MB
  unsigned short* wv_t   = (unsigned short*)(ws + off); off += (size_t)NEXP * NH * DIM * 2;  // 8 MB
  unsigned short* cont   = (unsigned short*)(ws + off);                                      // 16.8 MB

  hipMemsetAsync(counts, 0, sizeof(int) * NEXP * 2, stream);

  transpose_cvt_kernel<<<8192, 256, 0, stream>>>(w_keys, w_values, wk_t, wv_t);

  router_kernel<<<NTOK / RT, 128, 0, stream>>>(x, w_sel, counts, list);

  ffn_kernel<<<NEXP * 2 * SLOTS, 256, 0, stream>>>(x, wk_t, wv_t, out, cont,
                                                   counts, list);

  combine_kernel<<<NTOK * DIM / (256 * 8), 256, 0, stream>>>(cont, out);
}

// Round 7
// 288.704 us; speedup vs baseline: 1.5973x; 1.5973x over previous
//
#include <hip/hip_runtime.h>
#include <hip/hip_bf16.h>
#include <cstdint>
#include <cstddef>

// Problem constants: B=4,S=2048,D=1024,E=32,H=128,K=2
#define NTOK 8192
#define DIM  1024
#define NEXP 32
#define NH   128
#define TT   64               // tokens per FFN tile
#define BK   128              // K-chunk for phase A
#define LCAP2 512             // per-(expert,choice) capacity (R6-proven: never hit)
#define RTOK 16               // tokens per router block
#define FGRID 320             // >= max total tiles = 256 + 64 ceil-waste

typedef __attribute__((ext_vector_type(8))) short short8;
typedef __attribute__((ext_vector_type(4))) float float4_;

static __device__ __forceinline__ unsigned short f2bf(float f) {
  unsigned u = __float_as_uint(f);
  return (unsigned short)((u + 0x7fffu + ((u >> 16) & 1u)) >> 16);
}
static __device__ __forceinline__ float bf2f(unsigned short h) {
  return __uint_as_float(((unsigned)h) << 16);
}

// ---------------- Prep: per-expert weight transpose + fp32->bf16 -----------
// grid 8192: [0,4096) wk [E][D][H]->[E][H][D]; [4096,8192) wv [E][H][D]->[E][D][H]
__global__ __launch_bounds__(256) void transpose_cvt_kernel(
    const float* __restrict__ w_keys, const float* __restrict__ w_values,
    unsigned short* __restrict__ wk_t, unsigned short* __restrict__ wv_t)
{
  __shared__ float tile[32][33];
  const int bid = blockIdx.x;
  const int tid = threadIdx.x;
  const float* src; unsigned short* dst; int R, C, lb;
  if (bid < 4096) { src = w_keys;   dst = wk_t; R = DIM; C = NH;  lb = bid; }
  else            { src = w_values; dst = wv_t; R = NH;  C = DIM; lb = bid - 4096; }
  const int e   = lb >> 7;
  const int t   = lb & 127;
  const int tpc = C >> 5;
  const int r0  = (t / tpc) * 32;
  const int c0  = (t % tpc) * 32;
  const float* s = src + (size_t)e * R * C;
  unsigned short* d = dst + (size_t)e * R * C;

  const int i = tid >> 3;
  const int j = (tid & 7) * 4;
  float4 v = *(const float4*)(s + (size_t)(r0 + i) * C + c0 + j);
  tile[i][j] = v.x; tile[i][j + 1] = v.y; tile[i][j + 2] = v.z; tile[i][j + 3] = v.w;
  __syncthreads();
  unsigned lo = (unsigned)f2bf(tile[j + 0][i]) | ((unsigned)f2bf(tile[j + 1][i]) << 16);
  unsigned hi = (unsigned)f2bf(tile[j + 2][i]) | ((unsigned)f2bf(tile[j + 3][i]) << 16);
  uint2 u; u.x = lo; u.y = hi;
  *(uint2*)(d + (size_t)(c0 + i) * R + r0 + j) = u;
}

// ---------------- Router: all-register inner loop, broadcast x reads -------
// 512 blocks x 256 threads, 16 tokens/block.
// lane: e = tid&31 (expert), tq = tid>>5 (0..7) -> tokens tq*2, tq*2+1.
// All register arrays indexed by compile-time constants (full unroll) --
// R6's scratch-spill bug (dynamic index under partial unroll) is the lesson.
__global__ __launch_bounds__(256) void router_kernel(
    const float* __restrict__ x, const float* __restrict__ w_sel,
    int* __restrict__ counts, unsigned* __restrict__ list)
{
  __shared__ float sp[RTOK][33];
  const int tid  = threadIdx.x;
  const int tok0 = blockIdx.x * RTOK;
  const int e    = tid & 31;
  const int tq   = tid >> 5;          // 0..7

  const float* xr = x + (size_t)(tok0 + tq * 2) * DIM;
  const float* wr = w_sel + (size_t)e * DIM;

  float acc0 = 0.f, acc1 = 0.f;

  #pragma unroll 2
  for (int dc = 0; dc < DIM; dc += 16) {
    float4 w0 = *(const float4*)(wr + dc + 0);
    float4 w1 = *(const float4*)(wr + dc + 4);
    float4 w2 = *(const float4*)(wr + dc + 8);
    float4 w3 = *(const float4*)(wr + dc + 12);
    float4 xa0 = *(const float4*)(xr + dc + 0);
    float4 xa1 = *(const float4*)(xr + dc + 4);
    float4 xa2 = *(const float4*)(xr + dc + 8);
    float4 xa3 = *(const float4*)(xr + dc + 12);
    float4 xb0 = *(const float4*)(xr + DIM + dc + 0);
    float4 xb1 = *(const float4*)(xr + DIM + dc + 4);
    float4 xb2 = *(const float4*)(xr + DIM + dc + 8);
    float4 xb3 = *(const float4*)(xr + DIM + dc + 12);
    acc0 += xa0.x*w0.x + xa0.y*w0.y + xa0.z*w0.z + xa0.w*w0.w
          + xa1.x*w1.x + xa1.y*w1.y + xa1.z*w1.z + xa1.w*w1.w
          + xa2.x*w2.x + xa2.y*w2.y + xa2.z*w2.z + xa2.w*w2.w
          + xa3.x*w3.x + xa3.y*w3.y + xa3.z*w3.z + xa3.w*w3.w;
    acc1 += xb0.x*w0.x + xb0.y*w0.y + xb0.z*w0.z + xb0.w*w0.w
          + xb1.x*w1.x + xb1.y*w1.y + xb1.z*w1.z + xb1.w*w1.w
          + xb2.x*w2.x + xb2.y*w2.y + xb2.z*w2.z + xb2.w*w2.w
          + xb3.x*w3.x + xb3.y*w3.y + xb3.z*w3.z + xb3.w*w3.w;
  }

  sp[tq * 2 + 0][e] = acc0;
  sp[tq * 2 + 1][e] = acc1;
  __syncthreads();

  if (tid < RTOK) {
    const int t = tid;
    float m1 = -1e30f, m2 = -1e30f;
    int i1 = 0, i2 = 0;
    for (int ee = 0; ee < NEXP; ++ee) {
      float v = sp[t][ee];
      if (v > m1)      { m2 = m1; i2 = i1; m1 = v; i1 = ee; }
      else if (v > m2) { m2 = v; i2 = ee; }
    }
    const int token = tok0 + t;
    float g1 = 1.f / (1.f + __expf(-m1));
    float g2 = 1.f / (1.f + __expf(-m2));
    int p1 = atomicAdd(&counts[i1 * 2 + 0], 1);
    if (p1 < LCAP2) list[(i1 * 2 + 0) * LCAP2 + p1] = ((unsigned)f2bf(g1) << 16) | (unsigned)token;
    int p2 = atomicAdd(&counts[i2 * 2 + 1], 1);
    if (p2 < LCAP2) list[(i2 * 2 + 1) * LCAP2 + p2] = ((unsigned)f2bf(g2) << 16) | (unsigned)token;
  }
}

// ---------------- FFN: adaptive tiles, pipelined K-loop, no atomics --------
// grid FGRID; block finds its (expert,choice,tile) by prefix-scanning counts,
// so every launched block (up to ntiles) does exactly one 64-token tile.
// Phase A: S = relu(X @ Wk^T)*gate, M=64 N=128 K=1024; x prefetched to regs,
// B double-buffered in regs, single barrier per K-chunk.
// Phase B: O = S @ Wv^T, M=64 N=1024 K=128; A-frags hoisted across N-chunks.
// choice 0 -> f32 stores to out (full coverage); choice 1 -> bf16 cont.
__global__ __launch_bounds__(256, 1) void ffn_kernel(
    const float* __restrict__ x,
    const unsigned short* __restrict__ wk_t,   // bf16 [E][H][D]
    const unsigned short* __restrict__ wv_t,   // bf16 [E][D][H]
    float* __restrict__ out,
    unsigned short* __restrict__ cont,         // bf16 [NTOK][DIM]
    const int* __restrict__ counts, const unsigned* __restrict__ list)
{
  __shared__ __align__(16) unsigned short xs[2][TT][BK + 8];  // 34.8 KB
  __shared__ __align__(16) unsigned short ss[TT][NH + 8];     // 17.4 KB
  __shared__ int   cnts_s[64];
  __shared__ int   toks[TT];
  __shared__ float gates[TT];

  const int tid = threadIdx.x;
  if (tid < 64) cnts_s[tid] = min(counts[tid], LCAP2);
  __syncthreads();

  // adaptive tile lookup (uniform across block)
  int tile = blockIdx.x;
  int ec = -1, cnt = 0;
  for (int i = 0; i < 64; ++i) {
    int c  = cnts_s[i];
    int nt = (c + TT - 1) >> 6;
    if (ec < 0) {
      if (tile < nt) { ec = i; cnt = c; }
      else tile -= nt;
    }
  }
  if (ec < 0) return;
  const int e      = ec >> 1;
  const int choice = ec & 1;
  const int t0     = tile * TT;
  const int n_tok  = min(TT, cnt - t0);

  const unsigned* lst = list + (size_t)ec * LCAP2;
  if (tid < TT) {
    int valid = tid < n_tok;
    unsigned en = valid ? lst[t0 + tid] : 0u;
    toks[tid]  = (int)(en & 0xffffu);
    gates[tid] = valid ? bf2f((unsigned short)(en >> 16)) : 0.f;
  }
  __syncthreads();

  const int wave = tid >> 6;
  const int lane = tid & 63;
  const int quad = lane >> 4;
  const int l16  = lane & 15;
  const int st   = tid >> 2;          // staging token row 0..63
  const int sd   = (tid & 3) * 32;    // staging d-chunk

  const unsigned short* wkb = wk_t + (size_t)e * NH * DIM;
  const unsigned short* wvb = wv_t + (size_t)e * DIM * NH;
  const float* xrow = x + (size_t)toks[st] * DIM + sd;

  // ---- prologue: stage chunk 0 -> xs[0]
  {
    float4 f[8];
    #pragma unroll
    for (int q = 0; q < 8; ++q) f[q] = *(const float4*)(xrow + q * 4);
    #pragma unroll
    for (int p = 0; p < 4; ++p) {
      union { short8 s; __hip_bfloat162 h[4]; } u;
      u.h[0] = __float22bfloat162_rn(float2{f[2*p].x,   f[2*p].y});
      u.h[1] = __float22bfloat162_rn(float2{f[2*p].z,   f[2*p].w});
      u.h[2] = __float22bfloat162_rn(float2{f[2*p+1].x, f[2*p+1].y});
      u.h[3] = __float22bfloat162_rn(float2{f[2*p+1].z, f[2*p+1].w});
      *(short8*)&xs[0][st][sd + p * 8] = u.s;
    }
  }
  __syncthreads();

  // ---- Phase A: pipelined K-loop, B in reg dbuf, 1 barrier/chunk
  float4_ acc[4][2];
  #pragma unroll
  for (int mt = 0; mt < 4; ++mt)
    #pragma unroll
    for (int nt = 0; nt < 2; ++nt) acc[mt][nt] = (float4_){0.f, 0.f, 0.f, 0.f};

  short8 bA[2][4][2];
  #pragma unroll
  for (int kk = 0; kk < 4; ++kk)
    #pragma unroll
    for (int nt = 0; nt < 2; ++nt)
      bA[0][kk][nt] = *(const short8*)(wkb +
          (size_t)(wave * 32 + nt * 16 + l16) * DIM + kk * 32 + quad * 8);

  float4 xf[8];
  #pragma unroll
  for (int ci = 0; ci < 8; ++ci) {
    const int cur = ci & 1;
    // 1) prefetch next x chunk into regs (global, gathered rows)
    if (ci < 7) {
      #pragma unroll
      for (int q = 0; q < 8; ++q)
        xf[q] = *(const float4*)(xrow + (ci + 1) * BK + q * 4);
    }
    // 2) prefetch next B chunk into the other reg buffer (L2-hot weights)
    if (ci < 7) {
      #pragma unroll
      for (int kk = 0; kk < 4; ++kk)
        #pragma unroll
        for (int nt = 0; nt < 2; ++nt)
          bA[cur ^ 1][kk][nt] = *(const short8*)(wkb +
              (size_t)(wave * 32 + nt * 16 + l16) * DIM + (ci + 1) * BK + kk * 32 + quad * 8);
    }
    // 3) MFMA on current chunk
    #pragma unroll
    for (int kk = 0; kk < 4; ++kk) {
      short8 a[4];
      #pragma unroll
      for (int mt = 0; mt < 4; ++mt)
        a[mt] = *(const short8*)&xs[cur][mt * 16 + l16][kk * 32 + quad * 8];
      #pragma unroll
      for (int mt = 0; mt < 4; ++mt)
        #pragma unroll
        for (int nt = 0; nt < 2; ++nt)
          acc[mt][nt] = __builtin_amdgcn_mfma_f32_16x16x32_bf16(a[mt], bA[cur][kk][nt], acc[mt][nt], 0, 0, 0);
    }
    // 4) pack + store staged x into the other LDS buffer
    if (ci < 7) {
      #pragma unroll
      for (int p = 0; p < 4; ++p) {
        union { short8 s; __hip_bfloat162 h[4]; } u;
        u.h[0] = __float22bfloat162_rn(float2{xf[2*p].x,   xf[2*p].y});
        u.h[1] = __float22bfloat162_rn(float2{xf[2*p].z,   xf[2*p].w});
        u.h[2] = __float22bfloat162_rn(float2{xf[2*p+1].x, xf[2*p+1].y});
        u.h[3] = __float22bfloat162_rn(float2{xf[2*p+1].z, xf[2*p+1].w});
        *(short8*)&xs[cur ^ 1][st][sd + p * 8] = u.s;
      }
    }
    __syncthreads();
  }

  // epilogue A: relu * gate -> bf16 scores
  #pragma unroll
  for (int mt = 0; mt < 4; ++mt)
    #pragma unroll
    for (int nt = 0; nt < 2; ++nt)
      #pragma unroll
      for (int r = 0; r < 4; ++r) {
        int row = mt * 16 + quad * 4 + r;
        float v = fmaxf(acc[mt][nt][r], 0.f) * gates[row];
        ss[row][wave * 32 + nt * 16 + l16] = f2bf(v);
      }
  __syncthreads();

  // ---- Phase B: A-frags hoisted, full-unroll N-chunks
  short8 a2[4][4];
  #pragma unroll
  for (int mt = 0; mt < 4; ++mt)
    #pragma unroll
    for (int kk = 0; kk < 4; ++kk)
      a2[mt][kk] = *(const short8*)&ss[mt * 16 + l16][kk * 32 + quad * 8];

  #pragma unroll
  for (int nc = 0; nc < 4; ++nc) {
    const int colbase = wave * 256 + nc * 64;
    short8 b2[4][4];
    #pragma unroll
    for (int kk = 0; kk < 4; ++kk)
      #pragma unroll
      for (int nt = 0; nt < 4; ++nt)
        b2[kk][nt] = *(const short8*)(wvb +
            (size_t)(colbase + nt * 16 + l16) * NH + kk * 32 + quad * 8);

    float4_ o[4][4];
    #pragma unroll
    for (int mt = 0; mt < 4; ++mt)
      #pragma unroll
      for (int nt = 0; nt < 4; ++nt) o[mt][nt] = (float4_){0.f, 0.f, 0.f, 0.f};

    #pragma unroll
    for (int kk = 0; kk < 4; ++kk)
      #pragma unroll
      for (int mt = 0; mt < 4; ++mt)
        #pragma unroll
        for (int nt = 0; nt < 4; ++nt)
          o[mt][nt] = __builtin_amdgcn_mfma_f32_16x16x32_bf16(a2[mt][kk], b2[kk][nt], o[mt][nt], 0, 0, 0);

    if (choice == 0) {
      #pragma unroll
      for (int mt = 0; mt < 4; ++mt)
        #pragma unroll
        for (int r = 0; r < 4; ++r) {
          int row = mt * 16 + quad * 4 + r;
          if (row < n_tok) {
            float* basep = out + (size_t)toks[row] * DIM + colbase + l16;
            #pragma unroll
            for (int nt = 0; nt < 4; ++nt)
              basep[nt * 16] = o[mt][nt][r];
          }
        }
    } else {
      #pragma unroll
      for (int mt = 0; mt < 4; ++mt)
        #pragma unroll
        for (int r = 0; r < 4; ++r) {
          int row = mt * 16 + quad * 4 + r;
          if (row < n_tok) {
            unsigned short* basep = cont + (size_t)toks[row] * DIM + colbase + l16;
            #pragma unroll
            for (int nt = 0; nt < 4; ++nt)
              basep[nt * 16] = f2bf(o[mt][nt][r]);
          }
        }
    }
  }
}

// ---------------- Combine: out += cont (bf16) ------------------------------
__global__ __launch_bounds__(256) void combine_kernel(
    const unsigned short* __restrict__ cont, float* __restrict__ out)
{
  size_t i = ((size_t)blockIdx.x * 256 + threadIdx.x) * 8;
  uint4 c = *(const uint4*)(cont + i);
  float4 o0 = *(const float4*)(out + i);
  float4 o1 = *(const float4*)(out + i + 4);
  o0.x += bf2f((unsigned short)(c.x & 0xffff));
  o0.y += bf2f((unsigned short)(c.x >> 16));
  o0.z += bf2f((unsigned short)(c.y & 0xffff));
  o0.w += bf2f((unsigned short)(c.y >> 16));
  o1.x += bf2f((unsigned short)(c.z & 0xffff));
  o1.y += bf2f((unsigned short)(c.z >> 16));
  o1.z += bf2f((unsigned short)(c.w & 0xffff));
  o1.w += bf2f((unsigned short)(c.w >> 16));
  *(float4*)(out + i)     = o0;
  *(float4*)(out + i + 4) = o1;
}

extern "C" void kernel_launch(void* const* d_in, const int* in_sizes, int n_in,
                              void* d_out, int out_size, void* d_ws, size_t ws_size,
                              hipStream_t stream) {
  (void)in_sizes; (void)n_in; (void)ws_size; (void)out_size;
  const float* x        = (const float*)d_in[0];
  const float* w_sel    = (const float*)d_in[1];
  const float* w_keys   = (const float*)d_in[2];
  const float* w_values = (const float*)d_in[3];
  float* out = (float*)d_out;

  // workspace (~33.0 MB, R5/R6-proven size)
  char* ws = (char*)d_ws;
  size_t off = 0;
  int*            counts = (int*)(ws + off);            off += 4096;
  unsigned*       list   = (unsigned*)(ws + off);       off += (size_t)NEXP * 2 * LCAP2 * 4; // 128 KB
  unsigned short* wk_t   = (unsigned short*)(ws + off); off += (size_t)NEXP * NH * DIM * 2;  // 8 MB
  unsigned short* wv_t   = (unsigned short*)(ws + off); off += (size_t)NEXP * NH * DIM * 2;  // 8 MB
  unsigned short* cont   = (unsigned short*)(ws + off);                                      // 16.8 MB

  hipMemsetAsync(counts, 0, sizeof(int) * NEXP * 2, stream);

  transpose_cvt_kernel<<<8192, 256, 0, stream>>>(w_keys, w_values, wk_t, wv_t);

  router_kernel<<<NTOK / RTOK, 256, 0, stream>>>(x, w_sel, counts, list);

  ffn_kernel<<<FGRID, 256, 0, stream>>>(x, wk_t, wv_t, out, cont, counts, list);

  combine_kernel<<<NTOK * DIM / (256 * 8), 256, 0, stream>>>(cont, out);
}